// Round 17
// baseline (116.476 us; speedup 1.0000x reference)
//
#include <hip/hip_runtime.h>
#include <cstdint>
#include <cstddef>

#define B 8
#define L 1024
#define DM 512
#define H 8
#define LN_EPS 1e-5f

// workspace layout (float offsets)
#define U_OFF    0        // H*DM = 4096        uT[h*512+dm] = Wk[dm, h*64:] . wmap_k
#define SK_OFF   8192     // H*B*L = 65536      sk[(h*B+b)*L + l]
#define PART_OFF 81920    // 8*H*B*DM = 262144  vbar partials [js][h][b][dm]
#define OBP_OFF  348160   // H*B*DM = 32768     obase partials [h][b][n]

#define OUT_ELEMS ((size_t)B * L * DM)   // 4194304; attn matrix follows

typedef float f4 __attribute__((ext_vector_type(4)));

__device__ __forceinline__ float wave_sum(float s) {
#pragma unroll
    for (int off = 32; off > 0; off >>= 1) s += __shfl_xor(s, off, 64);
    return s;
}

// ---------- A: uT[h*512+dm] = Wk[dm, h*64:(h+1)*64] . wmap_k ----------
__global__ __launch_bounds__(64) void k_prep(const float* __restrict__ Wk,
                                             const float* __restrict__ Wmap,
                                             float* __restrict__ ws) {
    __shared__ float wm[64];
    int t = threadIdx.x;
    wm[t] = Wmap[64 + t];
    __syncthreads();
    int h = t >> 3, part = t & 7;
#pragma unroll
    for (int i = 0; i < 8; ++i) {
        int dm = blockIdx.x * 8 + i;
        const float* row = Wk + (size_t)dm * (H * 64) + h * 64 + part * 8;
        float s = 0.f;
#pragma unroll
        for (int d = 0; d < 8; ++d) s += row[d] * wm[part * 8 + d];
        s += __shfl_xor(s, 1, 64);
        s += __shfl_xor(s, 2, 64);
        s += __shfl_xor(s, 4, 64);
        if (part == 0) ws[U_OFF + h * DM + dm] = s;   // transposed layout
    }
}

// ---------- B: sk[h,b,l] = k[b,l,:] . uT[h,:]  (uT staged in LDS) ----------
__global__ __launch_bounds__(256) void k_sk(const float* __restrict__ k,
                                            float* __restrict__ ws) {
    __shared__ float uT[H][DM];   // 16 KB
    int t = threadIdx.x;
    for (int i = t * 4; i < H * DM; i += 1024)
        *(float4*)&uT[0][i] = *(const float4*)&ws[U_OFF + i];
    __syncthreads();
    int wave = t >> 6, lane = t & 63;
    int row = blockIdx.x * 4 + wave;  // b*L + l
    int b = row >> 10, l = row & 1023;
    const float* krow = k + (size_t)row * DM;
    float acc[8] = {0, 0, 0, 0, 0, 0, 0, 0};
#pragma unroll
    for (int s8 = 0; s8 < 8; ++s8) {
        int dm = s8 * 64 + lane;
        float kv = krow[dm];
#pragma unroll
        for (int h = 0; h < 8; ++h) acc[h] += kv * uT[h][dm];
    }
#pragma unroll
    for (int off = 32; off > 0; off >>= 1) {
#pragma unroll
        for (int h = 0; h < 8; ++h) acc[h] += __shfl_xor(acc[h], off, 64);
    }
    float vout = 0.f;
#pragma unroll
    for (int h = 0; h < 8; ++h) if (lane == h) vout = acc[h];
    if (lane < 8)
        ws[SK_OFF + ((size_t)(lane * B + b)) * L + l] = vout;
}

// ---------- C: vbar partials with fused softmax (no max-sub: |sk| ~ O(4)) ----------
// grid 256 = (js 0..7)<<5 | (b 0..7)<<2 | (quarter 0..3); 256 threads = 4 waves
__global__ __launch_bounds__(256) void k_vbar(const float* __restrict__ v,
                                              float* __restrict__ ws) {
    __shared__ float ps[H][128];  // 4 KB
    int blk = blockIdx.x;
    int quarter = blk & 3, b = (blk >> 2) & 7, js = blk >> 5;
    int w = threadIdx.x >> 6, lane = threadIdx.x & 63;
#pragma unroll
    for (int rep = 0; rep < 2; ++rep) {
        int h = w * 2 + rep;
        const float* rowp = ws + SK_OFF + ((size_t)(h * B + b)) * L;
        const f4* r4 = (const f4*)(rowp + lane * 16);
        float part = 0.f;
#pragma unroll
        for (int i = 0; i < 4; ++i) {
            f4 x = r4[i];
            part += __expf(x.x) + __expf(x.y) + __expf(x.z) + __expf(x.w);
        }
        float s = wave_sum(part);
        float inv = 1.f / s;
        float2 seg = *(const float2*)(rowp + js * 128 + lane * 2);
        ps[h][lane * 2 + 0] = __expf(seg.x) * inv;
        ps[h][lane * 2 + 1] = __expf(seg.y) * inv;
    }
    __syncthreads();
    int dm = quarter * 128 + (w & 1) * 64 + lane;
    int h0 = (w >> 1) * 4;
    const float* vb0 = v + ((size_t)b * L + js * 128) * DM + dm;
    float a0 = 0.f, a1 = 0.f, a2 = 0.f, a3 = 0.f;
#pragma unroll 4
    for (int jj = 0; jj < 128; ++jj) {
        float vv = vb0[(size_t)jj * DM];
        a0 += ps[h0 + 0][jj] * vv;
        a1 += ps[h0 + 1][jj] * vv;
        a2 += ps[h0 + 2][jj] * vv;
        a3 += ps[h0 + 3][jj] * vv;
    }
    ws[PART_OFF + ((size_t)((js * H + h0 + 0) * B + b)) * DM + dm] = a0;
    ws[PART_OFF + ((size_t)((js * H + h0 + 1) * B + b)) * DM + dm] = a1;
    ws[PART_OFF + ((size_t)((js * H + h0 + 2) * B + b)) * DM + dm] = a2;
    ws[PART_OFF + ((size_t)((js * H + h0 + 3) * B + b)) * DM + dm] = a3;
}

// ---------- D: ctx+obase merged, NO redundancy; grid 64 = h<<3 | b ----------
__global__ __launch_bounds__(256) void k_ctxob(const float* __restrict__ Wv,
                                               const float* __restrict__ bv,
                                               const float* __restrict__ Wfc,
                                               float* __restrict__ ws) {
    __shared__ float vb[DM];
    __shared__ float red[4][64];
    __shared__ float cx[64];
    int h = blockIdx.x >> 3, b = blockIdx.x & 7;
#pragma unroll
    for (int it = 0; it < 2; ++it) {
        int dm = threadIdx.x + it * 256;
        float s = 0.f;
#pragma unroll
        for (int js = 0; js < 8; ++js)
            s += ws[PART_OFF + ((size_t)((js * H + h) * B + b)) * DM + dm];
        vb[dm] = s;
    }
    __syncthreads();
    int w = threadIdx.x >> 6, d = threadIdx.x & 63;
    float acc = 0.f;
#pragma unroll 4
    for (int i = 0; i < 128; ++i) {
        int dm = w * 128 + i;
        acc += vb[dm] * Wv[(size_t)dm * DM + h * 64 + d];
    }
    red[w][d] = acc;
    __syncthreads();
    if (w == 0)
        cx[d] = red[0][d] + red[1][d] + red[2][d] + red[3][d] + bv[h * 64 + d];
    __syncthreads();
#pragma unroll
    for (int it = 0; it < 2; ++it) {
        int n = threadIdx.x + it * 256;
        float a = 0.f;
#pragma unroll 8
        for (int d2 = 0; d2 < 64; ++d2)
            a += cx[d2] * Wfc[(size_t)(h * 64 + d2) * DM + n];
        ws[OBP_OFF + (size_t)(h * B + b) * DM + n] = a;
    }
}

// ---------- E: out = LN(q+obase) [0,512)  ||  attn broadcast [512,1536) (64 rows/block) ----------
__global__ __launch_bounds__(256) void k_outattn(const float* __restrict__ q,
                                                 const float* __restrict__ bfc,
                                                 const float* __restrict__ lns,
                                                 const float* __restrict__ lnb,
                                                 float* __restrict__ ws,
                                                 float* __restrict__ out) {
    __shared__ float smem[516];   // out: obf[512]; attn: red at [512,516)
    int blk = blockIdx.x;
    int t = threadIdx.x, wave = t >> 6, lane = t & 63;
    if (blk >= 512) {
        // attn task: softmax(sk row hb), regular-store broadcast to 64 rows
        int blk2 = blk - 512;
        int hb = blk2 >> 4, ic = blk2 & 15;
        float4 s4 = *(const float4*)&ws[SK_OFF + (size_t)hb * L + t * 4];
        float e0 = __expf(s4.x), e1 = __expf(s4.y), e2 = __expf(s4.z), e3 = __expf(s4.w);
        float s = wave_sum(e0 + e1 + e2 + e3);
        if (lane == 0) smem[512 + wave] = s;
        __syncthreads();
        float inv = 1.f / (smem[512] + smem[513] + smem[514] + smem[515]);
        f4 p4 = {e0 * inv, e1 * inv, e2 * inv, e3 * inv};
        float* base = out + OUT_ELEMS + ((size_t)hb * L + (size_t)ic * 64) * L + t * 4;
#pragma unroll
        for (int r = 0; r < 64; ++r)
            *(f4*)(base + (size_t)r * L) = p4;   // A/B probe: regular (fill-path) stores
    } else {
        int rblk = blk;                  // 0..511, 16 rows each
        int b = rblk >> 6;
        for (int i = t; i < DM; i += 256) {
            float s = bfc[i];
#pragma unroll
            for (int hh = 0; hh < 8; ++hh)
                s += ws[OBP_OFF + (size_t)(hh * B + b) * DM + i];
            smem[i] = s;
        }
        __syncthreads();
#pragma unroll
        for (int rep = 0; rep < 4; ++rep) {
            int row = rblk * 16 + rep * 4 + wave;
            const float* qr = q + (size_t)row * DM;
            int d0 = lane * 8;
            float4 a = *(const float4*)(qr + d0);
            float4 c = *(const float4*)(qr + d0 + 4);
            float x[8] = {a.x + smem[d0],     a.y + smem[d0 + 1],
                          a.z + smem[d0 + 2], a.w + smem[d0 + 3],
                          c.x + smem[d0 + 4], c.y + smem[d0 + 5],
                          c.z + smem[d0 + 6], c.w + smem[d0 + 7]};
            float sum = 0.f, sq = 0.f;
#pragma unroll
            for (int i = 0; i < 8; ++i) { sum += x[i]; sq += x[i] * x[i]; }
#pragma unroll
            for (int off = 32; off > 0; off >>= 1) {
                sum += __shfl_xor(sum, off, 64);
                sq  += __shfl_xor(sq,  off, 64);
            }
            float mu = sum * (1.f / DM);
            float var = sq * (1.f / DM) - mu * mu;
            float invs = rsqrtf(var + LN_EPS);
            float4 sa = *(const float4*)(lns + d0);
            float4 sc = *(const float4*)(lns + d0 + 4);
            float4 ba = *(const float4*)(lnb + d0);
            float4 bb = *(const float4*)(lnb + d0 + 4);
            float sarr[8] = {sa.x, sa.y, sa.z, sa.w, sc.x, sc.y, sc.z, sc.w};
            float barr[8] = {ba.x, ba.y, ba.z, ba.w, bb.x, bb.y, bb.z, bb.w};
            float y[8];
#pragma unroll
            for (int i = 0; i < 8; ++i) y[i] = (x[i] - mu) * invs * sarr[i] + barr[i];
            float4 o0 = {y[0], y[1], y[2], y[3]};
            float4 o1 = {y[4], y[5], y[6], y[7]};
            *(float4*)(out + (size_t)row * DM + d0) = o0;
            *(float4*)(out + (size_t)row * DM + d0 + 4) = o1;
        }
    }
}

extern "C" void kernel_launch(void* const* d_in, const int* in_sizes, int n_in,
                              void* d_out, int out_size, void* d_ws, size_t ws_size,
                              hipStream_t stream) {
    const float* q    = (const float*)d_in[0];
    const float* k    = (const float*)d_in[1];
    const float* v    = (const float*)d_in[2];
    // d_in[3]=Wq, d_in[4]=bq, d_in[6]=bk, d_in[9][:64], d_in[10]=bmap all cancel in softmax
    const float* Wk   = (const float*)d_in[5];
    const float* Wv   = (const float*)d_in[7];
    const float* bv   = (const float*)d_in[8];
    const float* Wmap = (const float*)d_in[9];
    const float* Wfc  = (const float*)d_in[11];
    const float* bfc  = (const float*)d_in[12];
    const float* lns  = (const float*)d_in[13];
    const float* lnb  = (const float*)d_in[14];
    float* out = (float*)d_out;
    float* ws  = (float*)d_ws;

    hipLaunchKernelGGL(k_prep,    dim3(64),   dim3(64),  0, stream, Wk, Wmap, ws);
    hipLaunchKernelGGL(k_sk,      dim3(2048), dim3(256), 0, stream, k, ws);
    hipLaunchKernelGGL(k_vbar,    dim3(256),  dim3(256), 0, stream, v, ws);
    hipLaunchKernelGGL(k_ctxob,   dim3(64),   dim3(256), 0, stream, Wv, bv, Wfc, ws);
    hipLaunchKernelGGL(k_outattn, dim3(1536), dim3(256), 0, stream, q, bfc, lns, lnb, ws, out);
}

// Round 18
// 101.387 us; speedup vs baseline: 1.1488x; 1.1488x over previous
//
#include <hip/hip_runtime.h>
#include <cstdint>
#include <cstddef>

#define B 8
#define L 1024
#define DM 512
#define H 8
#define LN_EPS 1e-5f

// workspace layout (float offsets)
#define U_OFF    0        // H*DM = 4096        uT[h*512+dm] = Wk[dm, h*64:] . wmap_k
#define SK_OFF   8192     // H*B*L = 65536      sk[(h*B+b)*L + l]
#define PART_OFF 81920    // 8*H*B*DM = 262144  vbar partials [js][h][b][dm]
#define OBP_OFF  348160   // H*B*DM = 32768     obase partials [h][b][n]

#define OUT_ELEMS ((size_t)B * L * DM)   // 4194304; attn matrix follows

typedef float f4 __attribute__((ext_vector_type(4)));

__device__ __forceinline__ float wave_sum(float s) {
#pragma unroll
    for (int off = 32; off > 0; off >>= 1) s += __shfl_xor(s, off, 64);
    return s;
}

// ---------- A: uT[h*512+dm] = Wk[dm, h*64:(h+1)*64] . wmap_k ----------
__global__ __launch_bounds__(64) void k_prep(const float* __restrict__ Wk,
                                             const float* __restrict__ Wmap,
                                             float* __restrict__ ws) {
    __shared__ float wm[64];
    int t = threadIdx.x;
    wm[t] = Wmap[64 + t];
    __syncthreads();
    int h = t >> 3, part = t & 7;
#pragma unroll
    for (int i = 0; i < 8; ++i) {
        int dm = blockIdx.x * 8 + i;
        const float* row = Wk + (size_t)dm * (H * 64) + h * 64 + part * 8;
        float s = 0.f;
#pragma unroll
        for (int d = 0; d < 8; ++d) s += row[d] * wm[part * 8 + d];
        s += __shfl_xor(s, 1, 64);
        s += __shfl_xor(s, 2, 64);
        s += __shfl_xor(s, 4, 64);
        if (part == 0) ws[U_OFF + h * DM + dm] = s;   // transposed layout
    }
}

// ---------- B: sk[h,b,l] = k[b,l,:] . uT[h,:]  (uT staged in LDS) ----------
__global__ __launch_bounds__(256) void k_sk(const float* __restrict__ k,
                                            float* __restrict__ ws) {
    __shared__ float uT[H][DM];   // 16 KB
    int t = threadIdx.x;
    for (int i = t * 4; i < H * DM; i += 1024)
        *(float4*)&uT[0][i] = *(const float4*)&ws[U_OFF + i];
    __syncthreads();
    int wave = t >> 6, lane = t & 63;
    int row = blockIdx.x * 4 + wave;  // b*L + l
    int b = row >> 10, l = row & 1023;
    const float* krow = k + (size_t)row * DM;
    float acc[8] = {0, 0, 0, 0, 0, 0, 0, 0};
#pragma unroll
    for (int s8 = 0; s8 < 8; ++s8) {
        int dm = s8 * 64 + lane;
        float kv = krow[dm];
#pragma unroll
        for (int h = 0; h < 8; ++h) acc[h] += kv * uT[h][dm];
    }
#pragma unroll
    for (int off = 32; off > 0; off >>= 1) {
#pragma unroll
        for (int h = 0; h < 8; ++h) acc[h] += __shfl_xor(acc[h], off, 64);
    }
    float vout = 0.f;
#pragma unroll
    for (int h = 0; h < 8; ++h) if (lane == h) vout = acc[h];
    if (lane < 8)
        ws[SK_OFF + ((size_t)(lane * B + b)) * L + l] = vout;
}

// ---------- C: vbar partials with fused softmax (no max-sub: |sk| ~ O(4)) ----------
// grid 256 = (js 0..7)<<5 | (b 0..7)<<2 | (quarter 0..3); 256 threads = 4 waves
__global__ __launch_bounds__(256) void k_vbar(const float* __restrict__ v,
                                              float* __restrict__ ws) {
    __shared__ float ps[H][128];  // 4 KB
    int blk = blockIdx.x;
    int quarter = blk & 3, b = (blk >> 2) & 7, js = blk >> 5;
    int w = threadIdx.x >> 6, lane = threadIdx.x & 63;
#pragma unroll
    for (int rep = 0; rep < 2; ++rep) {
        int h = w * 2 + rep;
        const float* rowp = ws + SK_OFF + ((size_t)(h * B + b)) * L;
        const f4* r4 = (const f4*)(rowp + lane * 16);
        float part = 0.f;
#pragma unroll
        for (int i = 0; i < 4; ++i) {
            f4 x = r4[i];
            part += __expf(x.x) + __expf(x.y) + __expf(x.z) + __expf(x.w);
        }
        float s = wave_sum(part);
        float inv = 1.f / s;
        float2 seg = *(const float2*)(rowp + js * 128 + lane * 2);
        ps[h][lane * 2 + 0] = __expf(seg.x) * inv;
        ps[h][lane * 2 + 1] = __expf(seg.y) * inv;
    }
    __syncthreads();
    int dm = quarter * 128 + (w & 1) * 64 + lane;
    int h0 = (w >> 1) * 4;
    const float* vb0 = v + ((size_t)b * L + js * 128) * DM + dm;
    float a0 = 0.f, a1 = 0.f, a2 = 0.f, a3 = 0.f;
#pragma unroll 4
    for (int jj = 0; jj < 128; ++jj) {
        float vv = vb0[(size_t)jj * DM];
        a0 += ps[h0 + 0][jj] * vv;
        a1 += ps[h0 + 1][jj] * vv;
        a2 += ps[h0 + 2][jj] * vv;
        a3 += ps[h0 + 3][jj] * vv;
    }
    ws[PART_OFF + ((size_t)((js * H + h0 + 0) * B + b)) * DM + dm] = a0;
    ws[PART_OFF + ((size_t)((js * H + h0 + 1) * B + b)) * DM + dm] = a1;
    ws[PART_OFF + ((size_t)((js * H + h0 + 2) * B + b)) * DM + dm] = a2;
    ws[PART_OFF + ((size_t)((js * H + h0 + 3) * B + b)) * DM + dm] = a3;
}

// ---------- D: ctx+obase merged, NO redundancy; grid 64 = h<<3 | b ----------
__global__ __launch_bounds__(256) void k_ctxob(const float* __restrict__ Wv,
                                               const float* __restrict__ bv,
                                               const float* __restrict__ Wfc,
                                               float* __restrict__ ws) {
    __shared__ float vb[DM];
    __shared__ float red[4][64];
    __shared__ float cx[64];
    int h = blockIdx.x >> 3, b = blockIdx.x & 7;
#pragma unroll
    for (int it = 0; it < 2; ++it) {
        int dm = threadIdx.x + it * 256;
        float s = 0.f;
#pragma unroll
        for (int js = 0; js < 8; ++js)
            s += ws[PART_OFF + ((size_t)((js * H + h) * B + b)) * DM + dm];
        vb[dm] = s;
    }
    __syncthreads();
    int w = threadIdx.x >> 6, d = threadIdx.x & 63;
    float acc = 0.f;
#pragma unroll 4
    for (int i = 0; i < 128; ++i) {
        int dm = w * 128 + i;
        acc += vb[dm] * Wv[(size_t)dm * DM + h * 64 + d];
    }
    red[w][d] = acc;
    __syncthreads();
    if (w == 0)
        cx[d] = red[0][d] + red[1][d] + red[2][d] + red[3][d] + bv[h * 64 + d];
    __syncthreads();
#pragma unroll
    for (int it = 0; it < 2; ++it) {
        int n = threadIdx.x + it * 256;
        float a = 0.f;
#pragma unroll 8
        for (int d2 = 0; d2 < 64; ++d2)
            a += cx[d2] * Wfc[(size_t)(h * 64 + d2) * DM + n];
        ws[OBP_OFF + (size_t)(h * B + b) * DM + n] = a;
    }
}

// ---------- E: out = LN(q+obase) [0,512)  ||  attn broadcast [512,1536) (64 rows/block) ----------
__global__ __launch_bounds__(256) void k_outattn(const float* __restrict__ q,
                                                 const float* __restrict__ bfc,
                                                 const float* __restrict__ lns,
                                                 const float* __restrict__ lnb,
                                                 float* __restrict__ ws,
                                                 float* __restrict__ out) {
    __shared__ float smem[516];   // out: obf[512]; attn: red at [512,516)
    int blk = blockIdx.x;
    int t = threadIdx.x, wave = t >> 6, lane = t & 63;
    if (blk >= 512) {
        // attn task: softmax(sk row hb), NT-broadcast to 64 rows
        int blk2 = blk - 512;
        int hb = blk2 >> 4, ic = blk2 & 15;
        float4 s4 = *(const float4*)&ws[SK_OFF + (size_t)hb * L + t * 4];
        float e0 = __expf(s4.x), e1 = __expf(s4.y), e2 = __expf(s4.z), e3 = __expf(s4.w);
        float s = wave_sum(e0 + e1 + e2 + e3);
        if (lane == 0) smem[512 + wave] = s;
        __syncthreads();
        float inv = 1.f / (smem[512] + smem[513] + smem[514] + smem[515]);
        f4 p4 = {e0 * inv, e1 * inv, e2 * inv, e3 * inv};
        float* base = out + OUT_ELEMS + ((size_t)hb * L + (size_t)ic * 64) * L + t * 4;
#pragma unroll
        for (int r = 0; r < 64; ++r)
            __builtin_nontemporal_store(p4, (f4*)(base + (size_t)r * L));
    } else {
        int rblk = blk;                  // 0..511, 16 rows each
        int b = rblk >> 6;
        for (int i = t; i < DM; i += 256) {
            float s = bfc[i];
#pragma unroll
            for (int hh = 0; hh < 8; ++hh)
                s += ws[OBP_OFF + (size_t)(hh * B + b) * DM + i];
            smem[i] = s;
        }
        __syncthreads();
#pragma unroll
        for (int rep = 0; rep < 4; ++rep) {
            int row = rblk * 16 + rep * 4 + wave;
            const float* qr = q + (size_t)row * DM;
            int d0 = lane * 8;
            float4 a = *(const float4*)(qr + d0);
            float4 c = *(const float4*)(qr + d0 + 4);
            float x[8] = {a.x + smem[d0],     a.y + smem[d0 + 1],
                          a.z + smem[d0 + 2], a.w + smem[d0 + 3],
                          c.x + smem[d0 + 4], c.y + smem[d0 + 5],
                          c.z + smem[d0 + 6], c.w + smem[d0 + 7]};
            float sum = 0.f, sq = 0.f;
#pragma unroll
            for (int i = 0; i < 8; ++i) { sum += x[i]; sq += x[i] * x[i]; }
#pragma unroll
            for (int off = 32; off > 0; off >>= 1) {
                sum += __shfl_xor(sum, off, 64);
                sq  += __shfl_xor(sq,  off, 64);
            }
            float mu = sum * (1.f / DM);
            float var = sq * (1.f / DM) - mu * mu;
            float invs = rsqrtf(var + LN_EPS);
            float4 sa = *(const float4*)(lns + d0);
            float4 sc = *(const float4*)(lns + d0 + 4);
            float4 ba = *(const float4*)(lnb + d0);
            float4 bb = *(const float4*)(lnb + d0 + 4);
            float sarr[8] = {sa.x, sa.y, sa.z, sa.w, sc.x, sc.y, sc.z, sc.w};
            float barr[8] = {ba.x, ba.y, ba.z, ba.w, bb.x, bb.y, bb.z, bb.w};
            float y[8];
#pragma unroll
            for (int i = 0; i < 8; ++i) y[i] = (x[i] - mu) * invs * sarr[i] + barr[i];
            float4 o0 = {y[0], y[1], y[2], y[3]};
            float4 o1 = {y[4], y[5], y[6], y[7]};
            *(float4*)(out + (size_t)row * DM + d0) = o0;
            *(float4*)(out + (size_t)row * DM + d0 + 4) = o1;
        }
    }
}

extern "C" void kernel_launch(void* const* d_in, const int* in_sizes, int n_in,
                              void* d_out, int out_size, void* d_ws, size_t ws_size,
                              hipStream_t stream) {
    const float* q    = (const float*)d_in[0];
    const float* k    = (const float*)d_in[1];
    const float* v    = (const float*)d_in[2];
    // d_in[3]=Wq, d_in[4]=bq, d_in[6]=bk, d_in[9][:64], d_in[10]=bmap all cancel in softmax
    const float* Wk   = (const float*)d_in[5];
    const float* Wv   = (const float*)d_in[7];
    const float* bv   = (const float*)d_in[8];
    const float* Wmap = (const float*)d_in[9];
    const float* Wfc  = (const float*)d_in[11];
    const float* bfc  = (const float*)d_in[12];
    const float* lns  = (const float*)d_in[13];
    const float* lnb  = (const float*)d_in[14];
    float* out = (float*)d_out;
    float* ws  = (float*)d_ws;

    hipLaunchKernelGGL(k_prep,    dim3(64),   dim3(64),  0, stream, Wk, Wmap, ws);
    hipLaunchKernelGGL(k_sk,      dim3(2048), dim3(256), 0, stream, k, ws);
    hipLaunchKernelGGL(k_vbar,    dim3(256),  dim3(256), 0, stream, v, ws);
    hipLaunchKernelGGL(k_ctxob,   dim3(64),   dim3(256), 0, stream, Wv, bv, Wfc, ws);
    hipLaunchKernelGGL(k_outattn, dim3(1536), dim3(256), 0, stream, q, bfc, lns, lnb, ws, out);
}